// Round 5
// baseline (243.513 us; speedup 1.0000x reference)
//
#include <hip/hip_runtime.h>
#include <math.h>

typedef __bf16 bf16x8 __attribute__((ext_vector_type(8)));
typedef float  f32x4  __attribute__((ext_vector_type(4)));

#define BROWS 65536
#define DIM   512
#define NHEAD 64
#define NCOL  128

#define PRED_SZ  ((size_t)BROWS * NCOL)            // 8388608 floats
#define ARG_BASE PRED_SZ
#define LOSS_IDX (PRED_SZ + (size_t)BROWS * NHEAD)
// Borrowed inside argmax region (rewritten by fixup):
//   rows    0..511  : Bfrag, fragment-major bf16, 65536 bf16 = 32768 floats
//   rows 1056..1059 : 256 per-block loss partials
#define BF_OFF   ARG_BASE
#define PART_OFF (ARG_BASE + 1056 * (size_t)NHEAD)
#define FIX_ROWS 1088

// Bfrag: 128 frag-blocks of 512 bf16 (1 KB). Frag f = kc2*8 + nt (kc2 = k>>5).
// Elem (lane = q*16 + c, j) = B^T[col = nt*16+c][k = kc2*32 + q*8 + j].
// One frag-block = 64 lanes x 16 B contiguous -> global_load_lds width-16 ready,
// and ds_read_b128 at lane*16 is conflict-free.

__global__ __launch_bounds__(64) void spectral_kernel(
    const float* __restrict__ W, const float* __restrict__ u,
    __bf16* __restrict__ Bfrag)
{
    int n = blockIdx.x;       // head
    int lane = threadIdx.x;   // owns k = lane*8 .. lane*8+7

    const float* W0 = W + (size_t)n * 2 * DIM;
    const float* W1 = W0 + DIM;
    float u0 = u[2 * n], u1v = u[2 * n + 1];

    float w0[8], w1[8], vr[8];
    {
        float4 a0 = *(const float4*)(W0 + lane * 8);
        float4 a1 = *(const float4*)(W0 + lane * 8 + 4);
        float4 b0 = *(const float4*)(W1 + lane * 8);
        float4 b1 = *(const float4*)(W1 + lane * 8 + 4);
        w0[0]=a0.x; w0[1]=a0.y; w0[2]=a0.z; w0[3]=a0.w;
        w0[4]=a1.x; w0[5]=a1.y; w0[6]=a1.z; w0[7]=a1.w;
        w1[0]=b0.x; w1[1]=b0.y; w1[2]=b0.z; w1[3]=b0.w;
        w1[4]=b1.x; w1[5]=b1.y; w1[6]=b1.z; w1[7]=b1.w;
    }

    float ss = 0.f;
#pragma unroll
    for (int j = 0; j < 8; ++j) {
        vr[j] = fmaf(w0[j], u0, w1[j] * u1v);
        ss = fmaf(vr[j], vr[j], ss);
    }
#pragma unroll
    for (int m = 32; m >= 1; m >>= 1) ss += __shfl_xor(ss, m, 64);
    float inv_n = 1.f / fmaxf(sqrtf(ss), 1e-12f);

    float s0 = 0.f, s1 = 0.f;
#pragma unroll
    for (int j = 0; j < 8; ++j) {
        float v = vr[j] * inv_n;
        s0 = fmaf(w0[j], v, s0);
        s1 = fmaf(w1[j], v, s1);
    }
#pragma unroll
    for (int m = 32; m >= 1; m >>= 1) {
        s0 += __shfl_xor(s0, m, 64);
        s1 += __shfl_xor(s1, m, 64);
    }
    float nu = sqrtf(fmaf(s0, s0, s1 * s1));
    float inv_nu = 1.f / fmaxf(nu, 1e-12f);
    float sigma = fmaf(s0 * inv_nu, s0, (s1 * inv_nu) * s1);
    float inv_sigma = 1.f / sigma;

    int kc2 = lane >> 2;   // k>>5
    int q   = lane & 3;
#pragma unroll
    for (int o = 0; o < 2; ++o) {
        int col = 2 * n + o;
        int nt = col >> 4, cc = col & 15;
        bf16x8 hi;
#pragma unroll
        for (int j = 0; j < 8; ++j)
            hi[j] = (__bf16)((o ? w1[j] : w0[j]) * inv_sigma);
        *(bf16x8*)(Bfrag + (size_t)(kc2 * 8 + nt) * 512 + (q * 16 + cc) * 8) = hi;
    }
}

#define CVT8H(H, F0, F1) {            \
    H[0] = (__bf16)(F0).x; H[1] = (__bf16)(F0).y; \
    H[2] = (__bf16)(F0).z; H[3] = (__bf16)(F0).w; \
    H[4] = (__bf16)(F1).x; H[5] = (__bf16)(F1).y; \
    H[6] = (__bf16)(F1).z; H[7] = (__bf16)(F1).w; }

__device__ __forceinline__ void gld_lds16(const __bf16* g, __bf16* l) {
    __builtin_amdgcn_global_load_lds(
        (const __attribute__((address_space(1))) void*)g,
        (__attribute__((address_space(3))) void*)l, 16, 0, 0);
}

// 1024 threads = 16 waves; 1 block/CU (grid 256); wave owns 16 rows x 128 cols.
// B staged in two 64 KB LDS halves; only 3 barriers in the whole kernel.
__global__ __launch_bounds__(1024, 4) void gemm_fused(
    const float* __restrict__ A, const int* __restrict__ target,
    const __bf16* __restrict__ Bfrag, const float* __restrict__ bias,
    float* __restrict__ pred, float* __restrict__ outArg,
    float* __restrict__ partials)
{
    __shared__ __bf16 Bs[32768];   // 64 KB: one K-half (256 k) of B, frag-major

    int tid  = threadIdx.x;
    int wave = tid >> 6;
    int lane = tid & 63;
    int q = lane >> 4;    // 0..3
    int c = lane & 15;    // 0..15
    int rowBase = blockIdx.x * 256 + wave * 16;

    f32x4 acc[8] = {};

    const float* ap = A + (size_t)(rowBase + c) * DIM + q * 8;
    float4 x0 = *(const float4*)(ap);
    float4 x1 = *(const float4*)(ap + 4);

#pragma unroll
    for (int half = 0; half < 2; ++half) {
        if (half) __syncthreads();   // all waves done reading previous half
        {
            const __bf16* gB = Bfrag + (size_t)half * 32768
                             + (size_t)(wave * 4) * 512 + lane * 8;
            __bf16* lB = Bs + (size_t)(wave * 4) * 512;
#pragma unroll
            for (int t = 0; t < 4; ++t)
                gld_lds16(gB + t * 512, lB + t * 512);
        }
        __syncthreads();             // DMA complete; barrier-free from here

#pragma unroll
        for (int kc = 0; kc < 8; ++kc) {
            float4 n0, n1;
            if (!(half == 1 && kc == 7)) {
                int kn = half * 256 + kc * 32 + 32;
                n0 = *(const float4*)(ap + kn);
                n1 = *(const float4*)(ap + kn + 4);
            }
            bf16x8 ah;
            CVT8H(ah, x0, x1);
#pragma unroll
            for (int nt = 0; nt < 8; ++nt) {
                bf16x8 b = *(const bf16x8*)(Bs + (size_t)(kc * 8 + nt) * 512 + lane * 8);
                acc[nt] = __builtin_amdgcn_mfma_f32_16x16x32_bf16(ah, b, acc[nt], 0, 0, 0);
            }
            if (!(half == 1 && kc == 7)) { x0 = n0; x1 = n1; }
        }
    }

    // ---- epilogue: bias, pred store, LSE over heads (axis=1), argmax, loss ----
    float bv[8];
#pragma unroll
    for (int nt = 0; nt < 8; ++nt) bv[nt] = bias[nt * 16 + c];

    float lp = 0.f;
    bool doA = (rowBase >= FIX_ROWS);
#pragma unroll
    for (int reg = 0; reg < 4; ++reg) {
        int row = rowBase + q * 4 + reg;
        float p[8];
#pragma unroll
        for (int nt = 0; nt < 8; ++nt) p[nt] = acc[nt][reg] + bv[nt];
#pragma unroll
        for (int nt = 0; nt < 8; ++nt)
            pred[(size_t)row * NCOL + nt * 16 + c] = p[nt];

        // max/sum over own 8 cols (same parity o=c&1), butterfly lane bits 1..3
        float M = p[0];
#pragma unroll
        for (int nt = 1; nt < 8; ++nt) M = fmaxf(M, p[nt]);
        M = fmaxf(M, __shfl_xor(M, 2, 64));
        M = fmaxf(M, __shfl_xor(M, 4, 64));
        M = fmaxf(M, __shfl_xor(M, 8, 64));
        float Mx = __shfl_xor(M, 1, 64);

        float sE = 0.f;
#pragma unroll
        for (int nt = 0; nt < 8; ++nt) sE += expf(p[nt] - M);
        sE += __shfl_xor(sE, 2, 64);
        sE += __shfl_xor(sE, 4, 64);
        sE += __shfl_xor(sE, 8, 64);
        float sX = __shfl_xor(sE, 1, 64);

        float Lown = M + logf(sE);
        float Loth = Mx + logf(sX);
        float L0 = (c & 1) ? Loth : Lown;
        float L1 = (c & 1) ? Lown : Loth;

        float pn[8];
#pragma unroll
        for (int nt = 0; nt < 8; ++nt) pn[nt] = __shfl_xor(p[nt], 1, 64);

        if ((c & 1) == 0) {
            const int* trow = target + (size_t)row * NHEAD;
            float* arow = outArg + (size_t)row * NHEAD;
#pragma unroll
            for (int nt = 0; nt < 8; ++nt) {
                int head = nt * 8 + (c >> 1);
                int t = trow[head];
                lp += t ? (L1 - pn[nt]) : (L0 - p[nt]);
                if (doA) arow[head] = (pn[nt] > p[nt]) ? 1.f : 0.f;
            }
        }
    }

    // deterministic block partial: wave butterfly, fixed-order combine via LDS
#pragma unroll
    for (int m = 32; m >= 1; m >>= 1) lp += __shfl_xor(lp, m, 64);
    float* wsum = (float*)Bs;        // reuse: all Bs reads are done
    __syncthreads();
    if (lane == 0) wsum[wave] = lp;
    __syncthreads();
    if (tid == 0) {
        float s = 0.f;
#pragma unroll
        for (int w = 0; w < 16; ++w) s += wsum[w];
        partials[blockIdx.x] = s;
    }
}

// block 0: deterministic loss reduction (256 partials) + argmax rows 1056..1087
// blocks 1..66: argmax fixup rows 0..1055
__global__ __launch_bounds__(256) void fixup_kernel(
    const float* __restrict__ pred, const float* __restrict__ partials,
    float* __restrict__ outArg, float* __restrict__ lossOut)
{
    int tid = threadIdx.x;
    if (blockIdx.x == 0) {
        __shared__ double red[256];
        red[tid] = (double)partials[tid];
        __syncthreads();
        for (int m = 128; m >= 1; m >>= 1) {
            if (tid < m) red[tid] += red[tid + m];
            __syncthreads();
        }
        if (tid == 0) lossOut[0] = (float)(red[0] / 131072.0);
        __syncthreads();
        int row = 1056 + (tid >> 3);
        int hb = (tid & 7) * 8;
        const float* pr = pred + (size_t)row * NCOL;
        float* ar = outArg + (size_t)row * NHEAD;
#pragma unroll
        for (int h = 0; h < 8; ++h) {
            float a = pr[2 * (hb + h)], b = pr[2 * (hb + h) + 1];
            ar[hb + h] = (b > a) ? 1.f : 0.f;
        }
    } else {
        int row = (blockIdx.x - 1) * 16 + (tid >> 4);
        int hb = (tid & 15) * 4;
        const float* pr = pred + (size_t)row * NCOL;
        float* ar = outArg + (size_t)row * NHEAD;
#pragma unroll
        for (int h = 0; h < 4; ++h) {
            float a = pr[2 * (hb + h)], b = pr[2 * (hb + h) + 1];
            ar[hb + h] = (b > a) ? 1.f : 0.f;
        }
    }
}

extern "C" void kernel_launch(void* const* d_in, const int* in_sizes, int n_in,
                              void* d_out, int out_size, void* d_ws, size_t ws_size,
                              hipStream_t stream) {
    const float* feature = (const float*)d_in[0];   // [65536,512]
    const int*   target  = (const int*)d_in[1];     // [65536,64]
    const float* W       = (const float*)d_in[2];   // [64,2,512]
    const float* bias    = (const float*)d_in[3];   // [64,2]
    const float* u       = (const float*)d_in[4];   // [64,2]

    float* out     = (float*)d_out;
    float* pred    = out;
    float* outArg  = out + ARG_BASE;
    float* lossOut = out + LOSS_IDX;
    __bf16* Bfrag  = (__bf16*)(out + BF_OFF);
    float* partial = out + PART_OFF;

    spectral_kernel<<<NHEAD, 64, 0, stream>>>(W, u, Bfrag);
    gemm_fused<<<BROWS / 256, 1024, 0, stream>>>(feature, target, Bfrag, bias,
                                                 pred, outArg, partial);
    fixup_kernel<<<67, 256, 0, stream>>>(pred, partial, outArg, lossOut);
}

// Round 6
// 235.352 us; speedup vs baseline: 1.0347x; 1.0347x over previous
//
#include <hip/hip_runtime.h>
#include <math.h>

typedef __bf16 bf16x8 __attribute__((ext_vector_type(8)));
typedef float  f32x4  __attribute__((ext_vector_type(4)));

#define BROWS 65536
#define DIM   512
#define NHEAD 64
#define NCOL  128

#define PRED_SZ  ((size_t)BROWS * NCOL)            // 8388608 floats
#define ARG_BASE PRED_SZ
#define LOSS_IDX (PRED_SZ + (size_t)BROWS * NHEAD)
// Borrowed inside argmax region (rewritten by fixup):
//   rows    0..511  : Bfrag, fragment-major bf16, 65536 bf16 = 32768 floats
//   rows 1056..1063 : 512 per-block loss partials
#define BF_OFF   ARG_BASE
#define PART_OFF (ARG_BASE + 1056 * (size_t)NHEAD)
#define FIX_ROWS 1088

// Bfrag: 128 frag-blocks of 512 bf16 (1 KB). Frag f = kc2*8 + nt (kc2 = k>>5).
// Elem (lane = q*16 + c, j) = B^T[col = nt*16+c][k = kc2*32 + q*8 + j].
// One frag-block = 64 lanes x 16 B contiguous -> global_load_lds width-16 ready,
// ds_read_b128 at lane*16 conflict-free.

__global__ __launch_bounds__(64) void spectral_kernel(
    const float* __restrict__ W, const float* __restrict__ u,
    __bf16* __restrict__ Bfrag)
{
    int n = blockIdx.x;       // head
    int lane = threadIdx.x;   // owns k = lane*8 .. lane*8+7

    const float* W0 = W + (size_t)n * 2 * DIM;
    const float* W1 = W0 + DIM;
    float u0 = u[2 * n], u1v = u[2 * n + 1];

    float w0[8], w1[8], vr[8];
    {
        float4 a0 = *(const float4*)(W0 + lane * 8);
        float4 a1 = *(const float4*)(W0 + lane * 8 + 4);
        float4 b0 = *(const float4*)(W1 + lane * 8);
        float4 b1 = *(const float4*)(W1 + lane * 8 + 4);
        w0[0]=a0.x; w0[1]=a0.y; w0[2]=a0.z; w0[3]=a0.w;
        w0[4]=a1.x; w0[5]=a1.y; w0[6]=a1.z; w0[7]=a1.w;
        w1[0]=b0.x; w1[1]=b0.y; w1[2]=b0.z; w1[3]=b0.w;
        w1[4]=b1.x; w1[5]=b1.y; w1[6]=b1.z; w1[7]=b1.w;
    }

    float ss = 0.f;
#pragma unroll
    for (int j = 0; j < 8; ++j) {
        vr[j] = fmaf(w0[j], u0, w1[j] * u1v);
        ss = fmaf(vr[j], vr[j], ss);
    }
#pragma unroll
    for (int m = 32; m >= 1; m >>= 1) ss += __shfl_xor(ss, m, 64);
    float inv_n = 1.f / fmaxf(sqrtf(ss), 1e-12f);

    float s0 = 0.f, s1 = 0.f;
#pragma unroll
    for (int j = 0; j < 8; ++j) {
        float v = vr[j] * inv_n;
        s0 = fmaf(w0[j], v, s0);
        s1 = fmaf(w1[j], v, s1);
    }
#pragma unroll
    for (int m = 32; m >= 1; m >>= 1) {
        s0 += __shfl_xor(s0, m, 64);
        s1 += __shfl_xor(s1, m, 64);
    }
    float nu = sqrtf(fmaf(s0, s0, s1 * s1));
    float inv_nu = 1.f / fmaxf(nu, 1e-12f);
    float sigma = fmaf(s0 * inv_nu, s0, (s1 * inv_nu) * s1);
    float inv_sigma = 1.f / sigma;

    int kc2 = lane >> 2;   // k>>5
    int q   = lane & 3;
#pragma unroll
    for (int o = 0; o < 2; ++o) {
        int col = 2 * n + o;
        int nt = col >> 4, cc = col & 15;
        bf16x8 hi;
#pragma unroll
        for (int j = 0; j < 8; ++j)
            hi[j] = (__bf16)((o ? w1[j] : w0[j]) * inv_sigma);
        *(bf16x8*)(Bfrag + (size_t)(kc2 * 8 + nt) * 512 + (q * 16 + cc) * 8) = hi;
    }
}

#define CVT8H(H, F0, F1) {            \
    H[0] = (__bf16)(F0).x; H[1] = (__bf16)(F0).y; \
    H[2] = (__bf16)(F0).z; H[3] = (__bf16)(F0).w; \
    H[4] = (__bf16)(F1).x; H[5] = (__bf16)(F1).y; \
    H[6] = (__bf16)(F1).z; H[7] = (__bf16)(F1).w; }

__device__ __forceinline__ void gld_lds16(const __bf16* g, __bf16* l) {
    __builtin_amdgcn_global_load_lds(
        (const __attribute__((address_space(1))) void*)g,
        (__attribute__((address_space(3))) void*)l, 16, 0, 0);
}

// 512 threads = 8 waves; 128 rows/block; grid 512 -> 2 blocks/CU.
// B staged in two 64 KB LDS halves; A register-prefetch depth 4.
__global__ __launch_bounds__(512, 4) void gemm_fused(
    const float* __restrict__ A, const int* __restrict__ target,
    const __bf16* __restrict__ Bfrag, const float* __restrict__ bias,
    float* __restrict__ pred, float* __restrict__ outArg,
    float* __restrict__ partials)
{
    __shared__ __bf16 Bs[32768];   // 64 KB: one K-half (256 k) of B, frag-major

    int tid  = threadIdx.x;
    int wave = tid >> 6;
    int lane = tid & 63;
    int q = lane >> 4;    // 0..3
    int c = lane & 15;    // 0..15
    int rowBase = blockIdx.x * 128 + wave * 16;

    f32x4 acc[8] = {};

    const float* ap = A + (size_t)(rowBase + c) * DIM + q * 8;

    // prefetch pipeline: chunks 0..3 in flight (8 dwordx4 loads)
    float4 buf0[4], buf1[4];
#pragma unroll
    for (int i = 0; i < 4; ++i) {
        buf0[i] = *(const float4*)(ap + i * 32);
        buf1[i] = *(const float4*)(ap + i * 32 + 4);
    }

#pragma unroll
    for (int half = 0; half < 2; ++half) {
        if (half) __syncthreads();   // all waves done reading previous half
        {
            const __bf16* gB = Bfrag + (size_t)half * 32768
                             + (size_t)(wave * 8) * 512 + lane * 8;
            __bf16* lB = Bs + (size_t)(wave * 8) * 512;
#pragma unroll
            for (int t = 0; t < 8; ++t)
                gld_lds16(gB + t * 512, lB + t * 512);
        }
        __syncthreads();             // DMA complete; barrier-free K-loop follows

#pragma unroll
        for (int kc = 0; kc < 8; ++kc) {
            int it = half * 8 + kc;
            bf16x8 ah;
            CVT8H(ah, buf0[it & 3], buf1[it & 3]);
            if (it < 12) {           // re-issue this slot for chunk it+4
                buf0[it & 3] = *(const float4*)(ap + (it + 4) * 32);
                buf1[it & 3] = *(const float4*)(ap + (it + 4) * 32 + 4);
            }
#pragma unroll
            for (int nt = 0; nt < 8; ++nt) {
                bf16x8 b = *(const bf16x8*)(Bs + (size_t)(kc * 8 + nt) * 512 + lane * 8);
                acc[nt] = __builtin_amdgcn_mfma_f32_16x16x32_bf16(ah, b, acc[nt], 0, 0, 0);
            }
        }
    }

    // ---- epilogue: bias, pred store, LSE over heads (axis=1), argmax, loss ----
    float bv[8];
#pragma unroll
    for (int nt = 0; nt < 8; ++nt) bv[nt] = bias[nt * 16 + c];

    // batch the scattered target loads: issue all, single wait
    bool ce = ((c & 1) == 0);
    int tv[4][8];
    if (ce) {
#pragma unroll
        for (int reg = 0; reg < 4; ++reg) {
            const int* trow = target + (size_t)(rowBase + q * 4 + reg) * NHEAD + (c >> 1);
#pragma unroll
            for (int nt = 0; nt < 8; ++nt) tv[reg][nt] = trow[nt * 8];
        }
    }

    float lp = 0.f;
    bool doA = (rowBase >= FIX_ROWS);
#pragma unroll
    for (int reg = 0; reg < 4; ++reg) {
        int row = rowBase + q * 4 + reg;
        float p[8];
#pragma unroll
        for (int nt = 0; nt < 8; ++nt) p[nt] = acc[nt][reg] + bv[nt];
#pragma unroll
        for (int nt = 0; nt < 8; ++nt)
            pred[(size_t)row * NCOL + nt * 16 + c] = p[nt];

        // max/sum over own 8 cols (same parity o=c&1), butterfly lane bits 1..3
        float M = p[0];
#pragma unroll
        for (int nt = 1; nt < 8; ++nt) M = fmaxf(M, p[nt]);
        M = fmaxf(M, __shfl_xor(M, 2, 64));
        M = fmaxf(M, __shfl_xor(M, 4, 64));
        M = fmaxf(M, __shfl_xor(M, 8, 64));
        float Mx = __shfl_xor(M, 1, 64);

        float sE = 0.f;
#pragma unroll
        for (int nt = 0; nt < 8; ++nt) sE += expf(p[nt] - M);
        sE += __shfl_xor(sE, 2, 64);
        sE += __shfl_xor(sE, 4, 64);
        sE += __shfl_xor(sE, 8, 64);
        float sX = __shfl_xor(sE, 1, 64);

        float Lown = M + logf(sE);
        float Loth = Mx + logf(sX);
        float L0 = (c & 1) ? Loth : Lown;
        float L1 = (c & 1) ? Lown : Loth;

        float pn[8];
#pragma unroll
        for (int nt = 0; nt < 8; ++nt) pn[nt] = __shfl_xor(p[nt], 1, 64);

        if (ce) {
            float* arow = outArg + (size_t)row * NHEAD;
#pragma unroll
            for (int nt = 0; nt < 8; ++nt) {
                int t = tv[reg][nt];
                lp += t ? (L1 - pn[nt]) : (L0 - p[nt]);
                if (doA) arow[nt * 8 + (c >> 1)] = (pn[nt] > p[nt]) ? 1.f : 0.f;
            }
        }
    }

    // deterministic block partial: wave butterfly, fixed-order combine via LDS
#pragma unroll
    for (int m = 32; m >= 1; m >>= 1) lp += __shfl_xor(lp, m, 64);
    float* wsum = (float*)Bs;        // reuse: all Bs reads are done
    __syncthreads();
    if (lane == 0) wsum[wave] = lp;
    __syncthreads();
    if (tid == 0) {
        float s = 0.f;
#pragma unroll
        for (int w = 0; w < 8; ++w) s += wsum[w];
        partials[blockIdx.x] = s;
    }
}

// block 0: deterministic loss reduction (512 partials) + argmax rows 1056..1087
// blocks 1..66: argmax fixup rows 0..1055
__global__ __launch_bounds__(256) void fixup_kernel(
    const float* __restrict__ pred, const float* __restrict__ partials,
    float* __restrict__ outArg, float* __restrict__ lossOut)
{
    int tid = threadIdx.x;
    if (blockIdx.x == 0) {
        __shared__ double red[256];
        red[tid] = (double)partials[2 * tid] + (double)partials[2 * tid + 1];
        __syncthreads();
        for (int m = 128; m >= 1; m >>= 1) {
            if (tid < m) red[tid] += red[tid + m];
            __syncthreads();
        }
        if (tid == 0) lossOut[0] = (float)(red[0] / 131072.0);
        __syncthreads();
        int row = 1056 + (tid >> 3);
        int hb = (tid & 7) * 8;
        const float* pr = pred + (size_t)row * NCOL;
        float* ar = outArg + (size_t)row * NHEAD;
#pragma unroll
        for (int h = 0; h < 8; ++h) {
            float a = pr[2 * (hb + h)], b = pr[2 * (hb + h) + 1];
            ar[hb + h] = (b > a) ? 1.f : 0.f;
        }
    } else {
        int row = (blockIdx.x - 1) * 16 + (tid >> 4);
        int hb = (tid & 15) * 4;
        const float* pr = pred + (size_t)row * NCOL;
        float* ar = outArg + (size_t)row * NHEAD;
#pragma unroll
        for (int h = 0; h < 4; ++h) {
            float a = pr[2 * (hb + h)], b = pr[2 * (hb + h) + 1];
            ar[hb + h] = (b > a) ? 1.f : 0.f;
        }
    }
}

extern "C" void kernel_launch(void* const* d_in, const int* in_sizes, int n_in,
                              void* d_out, int out_size, void* d_ws, size_t ws_size,
                              hipStream_t stream) {
    const float* feature = (const float*)d_in[0];   // [65536,512]
    const int*   target  = (const int*)d_in[1];     // [65536,64]
    const float* W       = (const float*)d_in[2];   // [64,2,512]
    const float* bias    = (const float*)d_in[3];   // [64,2]
    const float* u       = (const float*)d_in[4];   // [64,2]

    float* out     = (float*)d_out;
    float* pred    = out;
    float* outArg  = out + ARG_BASE;
    float* lossOut = out + LOSS_IDX;
    __bf16* Bfrag  = (__bf16*)(out + BF_OFF);
    float* partial = out + PART_OFF;

    spectral_kernel<<<NHEAD, 64, 0, stream>>>(W, u, Bfrag);
    gemm_fused<<<BROWS / 128, 512, 0, stream>>>(feature, target, Bfrag, bias,
                                                pred, outArg, partial);
    fixup_kernel<<<67, 256, 0, stream>>>(pred, partial, outArg, lossOut);
}